// Round 2
// baseline (1071.404 us; speedup 1.0000x reference)
//
#include <hip/hip_runtime.h>

// CTC total-score forward (log-semiring), B=32 T=800 C=5000 L=100, S=201.
// Fully fused: one wave per batch element gathers its own emissions directly
// from log_probs with an 8-deep register prefetch ring (no emit buffer).
// Outputs: [tot_score, tot_frames, all_frames] as float32.

constexpr int B = 32;
constexpr int T = 800;
constexpr int C = 5000;
constexpr int L = 100;
constexpr int S = 2 * L + 1;   // 201
constexpr int PF = 8;          // prefetch depth (timesteps ahead)
constexpr float NEGV = -1e30f;

__device__ __forceinline__ float lse2(float a, float b) {
    const float m = fmaxf(a, b);
    return m + __logf(__expf(a - m) + __expf(b - m));
}
__device__ __forceinline__ float lse3(float a, float b, float c) {
    const float m = fmaxf(a, fmaxf(b, c));
    return m + __logf(__expf(a - m) + __expf(b - m) + __expf(c - m));
}

__global__ __launch_bounds__(64) void ctc_fused(
    const float* __restrict__ lp, const int* __restrict__ targets,
    const int* __restrict__ il_, const int* __restrict__ tl_,
    float* __restrict__ out)
{
    const int b    = blockIdx.x;
    const int lane = threadIdx.x;
    const int il   = il_[b];
    const int tl   = tl_[b];

    // Lane l owns states 4l..4l+3. Even states emit blank (class 0);
    // odd states 4l+1, 4l+3 emit targets[2l], targets[2l+1].
    const int l2 = 2 * lane;
    const int i1 = (l2     < L) ? l2     : L - 1;   // clamped (invalid lanes stay NEG)
    const int i3 = (l2 + 1 < L) ? l2 + 1 : L - 1;
    const int ip = (l2 - 1 >= 0) ? l2 - 1 : 0;
    const int tb = b * L;
    const int c1 = targets[tb + i1];
    const int c3 = targets[tb + i3];
    const int cp = targets[tb + ip];
    const bool skip1 = (lane == 0) ? true : (c1 != cp);   // state 1 always skip-ok
    const bool skip3 = (c3 != c1);

    const float* __restrict__ base = lp + (size_t)b * T * C;

    // ---- t = 0 init: alpha0[0] = blank(0), alpha0[1] = tgt0(0), rest NEG
    float a0, a1v, a2v, a3v;
    {
        const float bl0 = base[0];
        const float e01 = base[c1];       // lane 0 reads targets[0]
        a0  = (lane == 0) ? bl0 : NEGV;
        a1v = (lane == 0) ? e01 : NEGV;
        a2v = NEGV;
        a3v = NEGV;
    }

    // ---- prefetch ring for t = 1..PF
    float rb[PF], r1[PF], r3[PF];
#pragma unroll
    for (int k = 0; k < PF; ++k) {
        int t0 = 1 + k; if (t0 >= il) t0 = il - 1; if (t0 < 0) t0 = 0;
        const float* rowp = base + (size_t)t0 * C;
        rb[k] = rowp[0];
        r1[k] = rowp[c1];
        r3[k] = rowp[c3];
    }

    // ---- main recursion, PF-unrolled so the ring stays in registers
    int t = 1;
    while (t < il) {
#pragma unroll
        for (int k = 0; k < PF; ++k) {
            if (t < il) {
                const float bl = rb[k], e1 = r1[k], e3 = r3[k];

                // issue loads for t+PF (clamped; duplicate loads are harmless)
                int tn = t + PF; if (tn >= il) tn = il - 1;
                const float* rowp = base + (size_t)tn * C;
                rb[k] = rowp[0];
                r1[k] = rowp[c1];
                r3[k] = rowp[c3];

                float up3 = __shfl_up(a3v, 1);   // state 4l-1
                float up2 = __shfl_up(a2v, 1);   // state 4l-2
                if (lane == 0) { up3 = NEGV; up2 = NEGV; }

                // s=4l+0: a2=up3, no skip (blank)
                const float n0 = lse2(a0, up3) + bl;
                // s=4l+1: a2=a0, a3=up3 if skip1
                const float n1 = (skip1 ? lse3(a1v, a0, up3) : lse2(a1v, a0)) + e1;
                // s=4l+2: a2=a1v, no skip (blank)
                const float n2 = lse2(a2v, a1v) + bl;
                // s=4l+3: a2=a2v, a3=a1v if skip3
                const float n3 = (skip3 ? lse3(a3v, a2v, a1v) : lse2(a3v, a2v)) + e3;

                a0 = n0; a1v = n1; a2v = n2; a3v = n3;
            }
            ++t;
        }
    }

    // ---- extract final states 2*tl and 2*tl-1 via LDS
    __shared__ float sm[256];
    sm[4 * lane + 0] = a0;
    sm[4 * lane + 1] = a1v;
    sm[4 * lane + 2] = a2v;
    sm[4 * lane + 3] = a3v;
    __syncthreads();

    if (lane == 0) {
        const float va  = sm[2 * tl];
        const float vb  = sm[2 * tl - 1];
        const float tot = lse2(va, vb);
        const bool finite = tot > (NEGV * 0.5f);
        atomicAdd(out + 0, finite ? tot : 0.0f);
        atomicAdd(out + 1, finite ? (float)il : 0.0f);
        atomicAdd(out + 2, (float)il);
    }
}

extern "C" void kernel_launch(void* const* d_in, const int* in_sizes, int n_in,
                              void* d_out, int out_size, void* d_ws, size_t ws_size,
                              hipStream_t stream)
{
    const float* lp      = (const float*)d_in[0];   // (B,T,C) f32
    const int*   targets = (const int*)d_in[1];     // (B,L)
    const int*   il      = (const int*)d_in[2];     // (B,)
    const int*   tl      = (const int*)d_in[3];     // (B,)
    float* out = (float*)d_out;                     // 3 floats

    hipMemsetAsync(d_out, 0, (size_t)out_size * sizeof(float), stream);
    ctc_fused<<<B, 64, 0, stream>>>(lp, targets, il, tl, out);
}

// Round 3
// 805.382 us; speedup vs baseline: 1.3303x; 1.3303x over previous
//
#include <hip/hip_runtime.h>

// CTC total-score forward (log-semiring), B=32 T=800 C=5000 L=100, S=201.
// One block (5 waves) per batch element:
//   wave 0  : serial alpha recursion over t, states in registers (4/lane),
//             emissions read from LDS.
//   waves1-4: gather the NEXT 32-timestep chunk of emissions from log_probs
//             into a double-buffered LDS ring (13-deep load batches/lane).
// Outputs: [tot_score, tot_frames, all_frames] as float32.

constexpr int B  = 32;
constexpr int T  = 800;
constexpr int C  = 5000;
constexpr int L  = 100;
constexpr int S  = 2 * L + 1;    // 201
constexpr int SP = 204;          // padded row (16B-aligned rows: 204*4 = 816 = 51*16)
constexpr int CH = 32;           // timesteps per chunk
constexpr int CHE = CH * SP;     // 6528 floats per chunk buffer
constexpr int BLK = 320;         // 1 consumer wave + 4 producer waves
constexpr int NPROD = 256;
constexpr float NEGV = -1e30f;

__device__ __forceinline__ float lse2(float a, float b) {
    const float m = fmaxf(a, b);
    return m + __logf(__expf(a - m) + __expf(b - m));
}
__device__ __forceinline__ float lse3(float a, float b, float c) {
    const float m = fmaxf(a, fmaxf(b, c));
    return m + __logf(__expf(a - m) + __expf(b - m) + __expf(c - m));
}

__global__ __launch_bounds__(BLK) void ctc_fused(
    const float* __restrict__ lp, const int* __restrict__ targets,
    const int* __restrict__ il_, const int* __restrict__ tl_,
    float* __restrict__ out)
{
    __shared__ float buf[2][CHE];   // 52,224 B
    __shared__ int   tgt[L];
    __shared__ float sm[256];

    const int b   = blockIdx.x;
    const int tid = threadIdx.x;
    const int il  = il_[b];
    const int nch = (il + CH - 1) / CH;
    const float* __restrict__ base = lp + (size_t)b * T * C;

    if (tid < L) tgt[tid] = targets[b * L + tid];
    __syncthreads();

    // ---- consumer-wave constants (wave 0) ----
    const int lane = tid;            // only meaningful for tid < 64
    const int s0   = 4 * lane;
    bool skip1 = false, skip3 = false;
    bool v0 = false, v1 = false, v2c = false, v3 = false;
    int  off = 0;
    if (tid < 64) {
        const int l2 = 2 * lane;
        const int i1 = (l2     < L) ? l2     : L - 1;
        const int i3 = (l2 + 1 < L) ? l2 + 1 : L - 1;
        const int ip = (l2 - 1 >= 0) ? l2 - 1 : 0;
        const int c1i = tgt[i1], c3i = tgt[i3], cpi = tgt[ip];
        skip1 = (lane == 0) ? true : (c1i != cpi);
        skip3 = (c3i != c1i);
        v0  = (s0     < S);
        v1  = (s0 + 1 < S);
        v2c = (s0 + 2 < S);
        v3  = (s0 + 3 < S);
        off = (s0 <= 200) ? s0 : 200;   // clamped, stays 16B-aligned
    }

    float a0 = NEGV, a1v = NEGV, a2v = NEGV, a3v = NEGV;

    // ---- chunk loop: c = -1 is the producer prologue (fill chunk 0) ----
    for (int c = -1; c < nch; ++c) {
        if (tid >= 64) {
            // -------- producers: fill chunk c+1 --------
            const int c2 = c + 1;
            if (c2 < nch) {
                float* dst = buf[c2 & 1];
                const int tbase = c2 * CH;
                const int pid = tid - 64;
#pragma unroll
                for (int bat = 0; bat < 2; ++bat) {
                    float v[13];
                    int   fl[13];
#pragma unroll
                    for (int j = 0; j < 13; ++j) {
                        const int flat = (bat * 13 + j) * NPROD + pid;
                        fl[j] = flat;
                        float val = NEGV;
                        if (flat < CHE) {
                            const int r = flat / SP;
                            const int s = flat - r * SP;
                            const int t = tbase + r;
                            if (t < il) {
                                const int cls = ((s & 1) && s < S) ? tgt[s >> 1] : 0;
                                val = base[(size_t)t * C + cls];
                            }
                        }
                        v[j] = val;
                    }
#pragma unroll
                    for (int j = 0; j < 13; ++j)
                        if (fl[j] < CHE) dst[fl[j]] = v[j];
                }
            }
        } else if (c >= 0) {
            // -------- consumer: process chunk c --------
            const float* bp = buf[c & 1];
            const int tbase = c * CH;
            const int rmax  = (il - tbase < CH) ? (il - tbase) : CH;
            float4 e = *(const float4*)(bp + off);           // row 0
            for (int r = 0; r < rmax; ++r) {
                const float4 cur = e;
                if (r + 1 < rmax) e = *(const float4*)(bp + (r + 1) * SP + off);
                const int t = tbase + r;
                if (t == 0) {
                    a0  = (lane == 0) ? cur.x : NEGV;
                    a1v = (lane == 0) ? cur.y : NEGV;
                    a2v = NEGV; a3v = NEGV;
                } else {
                    float up3 = __shfl_up(a3v, 1);   // state 4l-1
                    float up2 = __shfl_up(a2v, 1);   // state 4l-2
                    if (lane == 0) { up3 = NEGV; up2 = NEGV; }
                    const float n0 = lse2(a0, up3) + cur.x;
                    const float n1 = (skip1 ? lse3(a1v, a0, up3) : lse2(a1v, a0)) + cur.y;
                    const float n2 = lse2(a2v, a1v) + cur.z;
                    const float n3 = (skip3 ? lse3(a3v, a2v, a1v) : lse2(a3v, a2v)) + cur.w;
                    a0  = v0  ? n0 : NEGV;
                    a1v = v1  ? n1 : NEGV;
                    a2v = v2c ? n2 : NEGV;
                    a3v = v3  ? n3 : NEGV;
                }
            }
        }
        __syncthreads();
    }

    // ---- final extraction (consumer wave) ----
    if (tid < 64) {
        sm[s0 + 0] = a0;
        sm[s0 + 1] = a1v;
        sm[s0 + 2] = a2v;
        sm[s0 + 3] = a3v;
    }
    __syncthreads();

    if (tid == 0) {
        const int tl = tl_[b];
        const float tot = lse2(sm[2 * tl], sm[2 * tl - 1]);
        const bool finite = tot > (NEGV * 0.5f);
        atomicAdd(out + 0, finite ? tot : 0.0f);
        atomicAdd(out + 1, finite ? (float)il : 0.0f);
        atomicAdd(out + 2, (float)il);
    }
}

extern "C" void kernel_launch(void* const* d_in, const int* in_sizes, int n_in,
                              void* d_out, int out_size, void* d_ws, size_t ws_size,
                              hipStream_t stream)
{
    const float* lp      = (const float*)d_in[0];   // (B,T,C) f32
    const int*   targets = (const int*)d_in[1];     // (B,L)
    const int*   il      = (const int*)d_in[2];     // (B,)
    const int*   tl      = (const int*)d_in[3];     // (B,)
    float* out = (float*)d_out;                     // 3 floats

    hipMemsetAsync(d_out, 0, (size_t)out_size * sizeof(float), stream);
    ctc_fused<<<B, BLK, 0, stream>>>(lp, targets, il, tl, out);
}